// Round 9
// baseline (212.568 us; speedup 1.0000x reference)
//
#include <hip/hip_runtime.h>

#define BATCH 100000

typedef float v2 __attribute__((ext_vector_type(2)));

__device__ __forceinline__ v2 fma2(v2 a, v2 b, v2 c) { return __builtin_elementwise_fma(a, b, c); }
__device__ __forceinline__ v2 relu2(v2 a) { v2 z = {0.f, 0.f}; return __builtin_elementwise_max(a, z); }
__device__ __forceinline__ v2 splat(float a) { v2 r = {a, a}; return r; }

// LDS float offsets (all 16B-aligned for ds_read_b128 merging)
#define PHI_W1 0
#define PHI_B1 256
#define PHI_W2 320
#define PHI_B2 1344
#define OBS_W1 1360
#define OBS_B1 1488
#define OBS_W2 1552
#define OBS_B2 2576
#define RHO_W1 2592
#define RHO_B1 3616
#define RHO_W2 3680
#define RHO_B2 3808
#define PSI_W1 3812
#define PSI_B1 4068
#define PSI_W2 4132
#define PSI_B2 4260
#define WTOT   4262

// 2 lanes per sample; lane t: phi neighbors [8t,8t+8), obs [4t,4t+4)
// (linearity: partial acc per lane, one shfl_xor to combine); rho/psi
// duplicated across the pair.
// R9: weights staged in LDS (17 KB/block, cooperative copy + 1 barrier).
// Rationale: s_load (SMEM) returns OUT-OF-ORDER -> lgkmcnt waits on SMEM
// are all-or-nothing drains; R7/R8 stalled ~59% on per-chunk SMEM flushes
// and the ~112-SGPR file can't pipeline deeper. ds_read is IN-ORDER ->
// fine-grained lgkmcnt(N) + VGPR destinations = deep pipelining. Uniform
// address = broadcast, conflict-free.
// launch_bounds MUST stay (256,4): (256,8) caps VGPR at 32 and spills
// (R3/R6 tripwire: WRITE_SIZE +25-31 MB). v_pk_fma_f32 = issue-slot
// savings only (f32 pipe 2 FLOP/lane/cyc; 157.3 TF spec).
__global__ __launch_bounds__(256, 4) void barrier_net(
    const float* __restrict__ x,
    const float* __restrict__ phi_w1, const float* __restrict__ phi_b1,
    const float* __restrict__ phi_w2, const float* __restrict__ phi_b2,
    const float* __restrict__ obs_w1, const float* __restrict__ obs_b1,
    const float* __restrict__ obs_w2, const float* __restrict__ obs_b2,
    const float* __restrict__ rho_w1, const float* __restrict__ rho_b1,
    const float* __restrict__ rho_w2, const float* __restrict__ rho_b2,
    const float* __restrict__ psi_w1, const float* __restrict__ psi_b1,
    const float* __restrict__ psi_w2, const float* __restrict__ psi_b2,
    float2* __restrict__ out)
{
    __shared__ float wlds[WTOT];

    // ---- cooperative weight staging (coalesced; stride-1 ds_write) ----
    {
        const float* srcs[16] = {phi_w1, phi_b1, phi_w2, phi_b2,
                                 obs_w1, obs_b1, obs_w2, obs_b2,
                                 rho_w1, rho_b1, rho_w2, rho_b2,
                                 psi_w1, psi_b1, psi_w2, psi_b2};
        const int offs[16]  = {PHI_W1, PHI_B1, PHI_W2, PHI_B2,
                               OBS_W1, OBS_B1, OBS_W2, OBS_B2,
                               RHO_W1, RHO_B1, RHO_W2, RHO_B2,
                               PSI_W1, PSI_B1, PSI_W2, PSI_B2};
        const int sizes[16] = {256, 64, 1024, 16, 128, 64, 1024, 16,
                               1024, 64, 128, 2, 256, 64, 128, 2};
        for (int a = 0; a < 16; ++a)
            for (int i = threadIdx.x; i < sizes[a]; i += 256)
                wlds[offs[a] + i] = srcs[a][i];
    }
    __syncthreads();

    const int tid = blockIdx.x * 256 + threadIdx.x;
    const int s = tid >> 1;
    const int t = tid & 1;
    if (s >= BATCH) return;
    const float* xr = x + (size_t)s * 85;

    auto L2 = [&](int i) -> v2 { return *(const v2*)(wlds + i); };
    auto L1f = [&](int i) -> float { return wlds[i]; };

    // ---- per-lane slice: 8 neighbors, 4 observations ----
    float nb[8][4];
    const int nbase = 5 + 32 * t;
#pragma unroll
    for (int n = 0; n < 8; ++n)
#pragma unroll
        for (int k = 0; k < 4; ++k)
            nb[n][k] = xr[nbase + 4 * n + k];

    float ob[4][2];
    const int obase = 69 + 8 * t;
#pragma unroll
    for (int o = 0; o < 4; ++o) {
        ob[o][0] = xr[obase + 2 * o];
        ob[o][1] = xr[obase + 2 * o + 1];
    }

    const float g0 = xr[0], g1 = xr[1];

    // ---- barrier partial over my 8 neighbors ----
    float bar0 = 0.f, bar1 = 0.f;
#pragma unroll
    for (int n = 0; n < 8; ++n) {
        float p0 = -nb[n][0], p1 = -nb[n][1];
        float r  = __builtin_amdgcn_sqrtf(fmaf(p0, p0, p1 * p1));
        float sc = 0.01f * __builtin_amdgcn_rcpf(r - 0.2f);
        bar0 = fmaf(sc, p0, bar0);
        bar1 = fmaf(sc, p1, bar1);
    }

    // ---- acc partial (16 as 8 v2): each lane carries half the bias ----
    v2 acc[8];
#pragma unroll
    for (int p = 0; p < 8; ++p)
        acc[p] = fma2(splat(8.f), L2(PHI_B2 + 2 * p),
                 fma2(splat(4.f), L2(OBS_B2 + 2 * p), splat(0.f)));

    // ---- phi: chunks of 8 h ----
#pragma unroll 2
    for (int c = 0; c < 8; ++c) {
        const int hb = c * 8;
        v2 hsv[4] = {{0.f,0.f},{0.f,0.f},{0.f,0.f},{0.f,0.f}};
#pragma unroll
        for (int n = 0; n < 8; ++n) {
#pragma unroll
            for (int p = 0; p < 4; ++p) {
                v2 tv = fma2(splat(nb[n][0]), L2(PHI_W1 + hb + 2 * p),
                        fma2(splat(nb[n][1]), L2(PHI_W1 + 64 + hb + 2 * p),
                        fma2(splat(nb[n][2]), L2(PHI_W1 + 128 + hb + 2 * p),
                        fma2(splat(nb[n][3]), L2(PHI_W1 + 192 + hb + 2 * p),
                                              L2(PHI_B1 + hb + 2 * p)))));
                hsv[p] += relu2(tv);
            }
        }
#pragma unroll
        for (int p = 0; p < 4; ++p) {
            const int r0 = PHI_W2 + (hb + 2 * p) * 16;
            v2 hx = splat(hsv[p].x), hy = splat(hsv[p].y);
#pragma unroll
            for (int q = 0; q < 8; ++q)
                acc[q] = fma2(hy, L2(r0 + 16 + 2 * q),
                         fma2(hx, L2(r0 + 2 * q), acc[q]));
        }
    }

    // ---- obs: same chunking ----
#pragma unroll 2
    for (int c = 0; c < 8; ++c) {
        const int hb = c * 8;
        v2 hsv[4] = {{0.f,0.f},{0.f,0.f},{0.f,0.f},{0.f,0.f}};
#pragma unroll
        for (int o = 0; o < 4; ++o) {
#pragma unroll
            for (int p = 0; p < 4; ++p) {
                v2 tv = fma2(splat(ob[o][0]), L2(OBS_W1 + hb + 2 * p),
                        fma2(splat(ob[o][1]), L2(OBS_W1 + 64 + hb + 2 * p),
                                              L2(OBS_B1 + hb + 2 * p)));
                hsv[p] += relu2(tv);
            }
        }
#pragma unroll
        for (int p = 0; p < 4; ++p) {
            const int r0 = OBS_W2 + (hb + 2 * p) * 16;
            v2 hx = splat(hsv[p].x), hy = splat(hsv[p].y);
#pragma unroll
            for (int q = 0; q < 8; ++q)
                acc[q] = fma2(hy, L2(r0 + 16 + 2 * q),
                         fma2(hx, L2(r0 + 2 * q), acc[q]));
        }
    }

    // ---- pair-sum: acc + barrier ----
#pragma unroll
    for (int p = 0; p < 8; ++p) {
        acc[p].x += __shfl_xor(acc[p].x, 1);
        acc[p].y += __shfl_xor(acc[p].y, 1);
    }
    bar0 += __shfl_xor(bar0, 1);
    bar1 += __shfl_xor(bar1, 1);

    // ---- rho: 16 -> 64 -> 2, duplicated, chunked ----
    v2 rr = L2(RHO_B2);
#pragma unroll 2
    for (int c = 0; c < 8; ++c) {
        const int hb = c * 8;
        v2 tt[4];
#pragma unroll
        for (int p = 0; p < 4; ++p)
            tt[p] = L2(RHO_B1 + hb + 2 * p);
#pragma unroll
        for (int j = 0; j < 8; ++j) {
            v2 ax = splat(acc[j].x), ay = splat(acc[j].y);
            const int rj0 = RHO_W1 + (2 * j) * 64 + hb;
            const int rj1 = RHO_W1 + (2 * j + 1) * 64 + hb;
#pragma unroll
            for (int p = 0; p < 4; ++p)
                tt[p] = fma2(ay, L2(rj1 + 2 * p),
                        fma2(ax, L2(rj0 + 2 * p), tt[p]));
        }
#pragma unroll
        for (int p = 0; p < 4; ++p) {
            v2 u = relu2(tt[p]);
            rr = fma2(splat(u.x), L2(RHO_W2 + 2 * (hb + 2 * p)), rr);
            rr = fma2(splat(u.y), L2(RHO_W2 + 2 * (hb + 2 * p) + 2), rr);
        }
    }

    // ---- psi: [r0, r1, g0, g1] -> 64 -> 2, duplicated, chunked ----
    v2 ee = L2(PSI_B2);
#pragma unroll 2
    for (int c = 0; c < 8; ++c) {
        const int hb = c * 8;
#pragma unroll
        for (int p = 0; p < 4; ++p) {
            v2 tv = fma2(splat(rr.x), L2(PSI_W1 + hb + 2 * p),
                    fma2(splat(rr.y), L2(PSI_W1 + 64 + hb + 2 * p),
                    fma2(splat(g0),   L2(PSI_W1 + 128 + hb + 2 * p),
                    fma2(splat(g1),   L2(PSI_W1 + 192 + hb + 2 * p),
                                      L2(PSI_B1 + hb + 2 * p)))));
            v2 u = relu2(tv);
            ee = fma2(splat(u.x), L2(PSI_W2 + 2 * (hb + 2 * p)), ee);
            ee = fma2(splat(u.y), L2(PSI_W2 + 2 * (hb + 2 * p) + 2), ee);
        }
    }

    if (t == 0) {
        float a0 = tanhf(tanhf(ee.x) + bar0);
        float a1 = tanhf(tanhf(ee.y) + bar1);
        out[s] = make_float2(2.f * a0, 2.f * a1);
    }
    (void)L1f;
}

extern "C" void kernel_launch(void* const* d_in, const int* in_sizes, int n_in,
                              void* d_out, int out_size, void* d_ws, size_t ws_size,
                              hipStream_t stream) {
    const int threads = BATCH * 2;
    dim3 grid((threads + 255) / 256), block(256);
    barrier_net<<<grid, block, 0, stream>>>(
        (const float*)d_in[0],
        (const float*)d_in[1],  (const float*)d_in[2],  (const float*)d_in[3],  (const float*)d_in[4],
        (const float*)d_in[5],  (const float*)d_in[6],  (const float*)d_in[7],  (const float*)d_in[8],
        (const float*)d_in[9],  (const float*)d_in[10], (const float*)d_in[11], (const float*)d_in[12],
        (const float*)d_in[13], (const float*)d_in[14], (const float*)d_in[15], (const float*)d_in[16],
        (float2*)d_out);
}

// Round 10
// 209.267 us; speedup vs baseline: 1.0158x; 1.0158x over previous
//
#include <hip/hip_runtime.h>

#define BATCH 100000

typedef float v2 __attribute__((ext_vector_type(2)));

__device__ __forceinline__ v2 fma2(v2 a, v2 b, v2 c) { return __builtin_elementwise_fma(a, b, c); }
__device__ __forceinline__ v2 relu2(v2 a) { v2 z = {0.f, 0.f}; return __builtin_elementwise_max(a, z); }
__device__ __forceinline__ v2 splat(float a) { v2 r = {a, a}; return r; }

// LDS float offsets (all 16B-aligned for ds_read_b128 merging)
#define PHI_W1 0
#define PHI_B1 256
#define PHI_W2 320
#define PHI_B2 1344
#define OBS_W1 1360
#define OBS_B1 1488
#define OBS_W2 1552
#define OBS_B2 2576
#define RHO_W1 2592
#define RHO_B1 3616
#define RHO_W2 3680
#define RHO_B2 3808
#define PSI_W1 3812
#define PSI_B1 4068
#define PSI_W2 4132
#define PSI_B2 4260
#define WTOT   4262

// 2 lanes per sample; lane t: phi neighbors [8t,8t+8), obs [4t,4t+4)
// (linearity: partial acc per lane, one shfl_xor to combine); rho/psi
// duplicated across the pair.
// Weights staged in LDS: s_load (SMEM) returns OUT-OF-ORDER -> lgkmcnt
// waits on SMEM are all-or-nothing drains (R7/R8 ~59% stalled on ~600
// drain points); ds_read is IN-ORDER -> fine-grained lgkmcnt(N) waits,
// VGPR destinations, deep pipelining. Uniform address = broadcast.
// R10: staging is STRAIGHT-LINE code. R9's pointer-array staging loop
// (srcs[16] indexed by runtime var) went to per-thread SCRATCH: +72 MB
// WRITE / +108 MB FETCH -> kernel was scratch-BW-bound at 126 us.
// launch_bounds MUST stay (256,4): (256,8) caps VGPR at 32 and spills
// (R3/R6 tripwire: WRITE_SIZE must stay ~781 KB).
__global__ __launch_bounds__(256, 4) void barrier_net(
    const float* __restrict__ x,
    const float* __restrict__ phi_w1, const float* __restrict__ phi_b1,
    const float* __restrict__ phi_w2, const float* __restrict__ phi_b2,
    const float* __restrict__ obs_w1, const float* __restrict__ obs_b1,
    const float* __restrict__ obs_w2, const float* __restrict__ obs_b2,
    const float* __restrict__ rho_w1, const float* __restrict__ rho_b1,
    const float* __restrict__ rho_w2, const float* __restrict__ rho_b2,
    const float* __restrict__ psi_w1, const float* __restrict__ psi_b1,
    const float* __restrict__ psi_w2, const float* __restrict__ psi_b2,
    float2* __restrict__ out)
{
    __shared__ float wlds[WTOT];

    // ---- cooperative weight staging: straight-line, SGPR pointers only ----
    {
        const int tx = threadIdx.x;
        wlds[PHI_W1 + tx] = phi_w1[tx];                      // 256
        wlds[PSI_W1 + tx] = psi_w1[tx];                      // 256
#pragma unroll
        for (int k = 0; k < 4; ++k) {                        // 1024 each
            wlds[PHI_W2 + 256 * k + tx] = phi_w2[256 * k + tx];
            wlds[OBS_W2 + 256 * k + tx] = obs_w2[256 * k + tx];
            wlds[RHO_W1 + 256 * k + tx] = rho_w1[256 * k + tx];
        }
        if (tx < 128) {
            wlds[OBS_W1 + tx] = obs_w1[tx];
            wlds[RHO_W2 + tx] = rho_w2[tx];
            wlds[PSI_W2 + tx] = psi_w2[tx];
        }
        if (tx < 64) {
            wlds[PHI_B1 + tx] = phi_b1[tx];
            wlds[OBS_B1 + tx] = obs_b1[tx];
            wlds[RHO_B1 + tx] = rho_b1[tx];
            wlds[PSI_B1 + tx] = psi_b1[tx];
        }
        if (tx < 16) {
            wlds[PHI_B2 + tx] = phi_b2[tx];
            wlds[OBS_B2 + tx] = obs_b2[tx];
        }
        if (tx < 2) {
            wlds[RHO_B2 + tx] = rho_b2[tx];
            wlds[PSI_B2 + tx] = psi_b2[tx];
        }
    }
    __syncthreads();

    const int tid = blockIdx.x * 256 + threadIdx.x;
    const int s = tid >> 1;
    const int t = tid & 1;
    if (s >= BATCH) return;
    const float* xr = x + (size_t)s * 85;

    auto L2 = [&](int i) -> v2 { return *(const v2*)(wlds + i); };

    // ---- per-lane slice: 8 neighbors, 4 observations ----
    float nb[8][4];
    const int nbase = 5 + 32 * t;
#pragma unroll
    for (int n = 0; n < 8; ++n)
#pragma unroll
        for (int k = 0; k < 4; ++k)
            nb[n][k] = xr[nbase + 4 * n + k];

    float ob[4][2];
    const int obase = 69 + 8 * t;
#pragma unroll
    for (int o = 0; o < 4; ++o) {
        ob[o][0] = xr[obase + 2 * o];
        ob[o][1] = xr[obase + 2 * o + 1];
    }

    const float g0 = xr[0], g1 = xr[1];

    // ---- barrier partial over my 8 neighbors ----
    float bar0 = 0.f, bar1 = 0.f;
#pragma unroll
    for (int n = 0; n < 8; ++n) {
        float p0 = -nb[n][0], p1 = -nb[n][1];
        float r  = __builtin_amdgcn_sqrtf(fmaf(p0, p0, p1 * p1));
        float sc = 0.01f * __builtin_amdgcn_rcpf(r - 0.2f);
        bar0 = fmaf(sc, p0, bar0);
        bar1 = fmaf(sc, p1, bar1);
    }

    // ---- acc partial (16 as 8 v2): each lane carries half the bias ----
    v2 acc[8];
#pragma unroll
    for (int p = 0; p < 8; ++p)
        acc[p] = fma2(splat(8.f), L2(PHI_B2 + 2 * p),
                 fma2(splat(4.f), L2(OBS_B2 + 2 * p), splat(0.f)));

    // ---- phi: chunks of 8 h ----
#pragma unroll 2
    for (int c = 0; c < 8; ++c) {
        const int hb = c * 8;
        v2 hsv[4] = {{0.f,0.f},{0.f,0.f},{0.f,0.f},{0.f,0.f}};
#pragma unroll
        for (int n = 0; n < 8; ++n) {
#pragma unroll
            for (int p = 0; p < 4; ++p) {
                v2 tv = fma2(splat(nb[n][0]), L2(PHI_W1 + hb + 2 * p),
                        fma2(splat(nb[n][1]), L2(PHI_W1 + 64 + hb + 2 * p),
                        fma2(splat(nb[n][2]), L2(PHI_W1 + 128 + hb + 2 * p),
                        fma2(splat(nb[n][3]), L2(PHI_W1 + 192 + hb + 2 * p),
                                              L2(PHI_B1 + hb + 2 * p)))));
                hsv[p] += relu2(tv);
            }
        }
#pragma unroll
        for (int p = 0; p < 4; ++p) {
            const int r0 = PHI_W2 + (hb + 2 * p) * 16;
            v2 hx = splat(hsv[p].x), hy = splat(hsv[p].y);
#pragma unroll
            for (int q = 0; q < 8; ++q)
                acc[q] = fma2(hy, L2(r0 + 16 + 2 * q),
                         fma2(hx, L2(r0 + 2 * q), acc[q]));
        }
    }

    // ---- obs: same chunking ----
#pragma unroll 2
    for (int c = 0; c < 8; ++c) {
        const int hb = c * 8;
        v2 hsv[4] = {{0.f,0.f},{0.f,0.f},{0.f,0.f},{0.f,0.f}};
#pragma unroll
        for (int o = 0; o < 4; ++o) {
#pragma unroll
            for (int p = 0; p < 4; ++p) {
                v2 tv = fma2(splat(ob[o][0]), L2(OBS_W1 + hb + 2 * p),
                        fma2(splat(ob[o][1]), L2(OBS_W1 + 64 + hb + 2 * p),
                                              L2(OBS_B1 + hb + 2 * p)));
                hsv[p] += relu2(tv);
            }
        }
#pragma unroll
        for (int p = 0; p < 4; ++p) {
            const int r0 = OBS_W2 + (hb + 2 * p) * 16;
            v2 hx = splat(hsv[p].x), hy = splat(hsv[p].y);
#pragma unroll
            for (int q = 0; q < 8; ++q)
                acc[q] = fma2(hy, L2(r0 + 16 + 2 * q),
                         fma2(hx, L2(r0 + 2 * q), acc[q]));
        }
    }

    // ---- pair-sum: acc + barrier ----
#pragma unroll
    for (int p = 0; p < 8; ++p) {
        acc[p].x += __shfl_xor(acc[p].x, 1);
        acc[p].y += __shfl_xor(acc[p].y, 1);
    }
    bar0 += __shfl_xor(bar0, 1);
    bar1 += __shfl_xor(bar1, 1);

    // ---- rho: 16 -> 64 -> 2, duplicated, chunked ----
    v2 rr = L2(RHO_B2);
#pragma unroll 2
    for (int c = 0; c < 8; ++c) {
        const int hb = c * 8;
        v2 tt[4];
#pragma unroll
        for (int p = 0; p < 4; ++p)
            tt[p] = L2(RHO_B1 + hb + 2 * p);
#pragma unroll
        for (int j = 0; j < 8; ++j) {
            v2 ax = splat(acc[j].x), ay = splat(acc[j].y);
            const int rj0 = RHO_W1 + (2 * j) * 64 + hb;
            const int rj1 = RHO_W1 + (2 * j + 1) * 64 + hb;
#pragma unroll
            for (int p = 0; p < 4; ++p)
                tt[p] = fma2(ay, L2(rj1 + 2 * p),
                        fma2(ax, L2(rj0 + 2 * p), tt[p]));
        }
#pragma unroll
        for (int p = 0; p < 4; ++p) {
            v2 u = relu2(tt[p]);
            rr = fma2(splat(u.x), L2(RHO_W2 + 2 * (hb + 2 * p)), rr);
            rr = fma2(splat(u.y), L2(RHO_W2 + 2 * (hb + 2 * p) + 2), rr);
        }
    }

    // ---- psi: [r0, r1, g0, g1] -> 64 -> 2, duplicated, chunked ----
    v2 ee = L2(PSI_B2);
#pragma unroll 2
    for (int c = 0; c < 8; ++c) {
        const int hb = c * 8;
#pragma unroll
        for (int p = 0; p < 4; ++p) {
            v2 tv = fma2(splat(rr.x), L2(PSI_W1 + hb + 2 * p),
                    fma2(splat(rr.y), L2(PSI_W1 + 64 + hb + 2 * p),
                    fma2(splat(g0),   L2(PSI_W1 + 128 + hb + 2 * p),
                    fma2(splat(g1),   L2(PSI_W1 + 192 + hb + 2 * p),
                                      L2(PSI_B1 + hb + 2 * p)))));
            v2 u = relu2(tv);
            ee = fma2(splat(u.x), L2(PSI_W2 + 2 * (hb + 2 * p)), ee);
            ee = fma2(splat(u.y), L2(PSI_W2 + 2 * (hb + 2 * p) + 2), ee);
        }
    }

    if (t == 0) {
        float a0 = tanhf(tanhf(ee.x) + bar0);
        float a1 = tanhf(tanhf(ee.y) + bar1);
        out[s] = make_float2(2.f * a0, 2.f * a1);
    }
}

extern "C" void kernel_launch(void* const* d_in, const int* in_sizes, int n_in,
                              void* d_out, int out_size, void* d_ws, size_t ws_size,
                              hipStream_t stream) {
    const int threads = BATCH * 2;
    dim3 grid((threads + 255) / 256), block(256);
    barrier_net<<<grid, block, 0, stream>>>(
        (const float*)d_in[0],
        (const float*)d_in[1],  (const float*)d_in[2],  (const float*)d_in[3],  (const float*)d_in[4],
        (const float*)d_in[5],  (const float*)d_in[6],  (const float*)d_in[7],  (const float*)d_in[8],
        (const float*)d_in[9],  (const float*)d_in[10], (const float*)d_in[11], (const float*)d_in[12],
        (const float*)d_in[13], (const float*)d_in[14], (const float*)d_in[15], (const float*)d_in[16],
        (float2*)d_out);
}

// Round 11
// 158.706 us; speedup vs baseline: 1.3394x; 1.3186x over previous
//
#include <hip/hip_runtime.h>

#define BATCH 100000

typedef float v2 __attribute__((ext_vector_type(2)));

__device__ __forceinline__ v2 fma2(v2 a, v2 b, v2 c) { return __builtin_elementwise_fma(a, b, c); }
__device__ __forceinline__ v2 relu2(v2 a) { v2 z = {0.f, 0.f}; return __builtin_elementwise_max(a, z); }
__device__ __forceinline__ v2 splat(float a) { v2 r = {a, a}; return r; }

// LDS float offsets (all 16B-aligned for ds_read_b128 merging)
#define PHI_W1 0
#define PHI_B1 256
#define PHI_W2 320
#define PHI_B2 1344
#define OBS_W1 1360
#define OBS_B1 1488
#define OBS_W2 1552
#define OBS_B2 2576
#define RHO_W1 2592
#define RHO_B1 3616
#define RHO_W2 3680
#define RHO_B2 3808
#define PSI_W1 3812
#define PSI_B1 4068
#define PSI_W2 4132
#define PSI_B2 4260
#define WTOT   4262

// 2 lanes per sample; lane t: phi neighbors [8t,8t+8), obs [4t,4t+4)
// (linearity: partial acc per lane, one shfl_xor to combine); rho/psi
// duplicated across the pair.
// Weights staged in LDS: s_load (SMEM) is OUT-OF-ORDER -> lgkmcnt waits
// on SMEM are all-or-nothing drains (R7/R8 ~59% stalled); ds_read is
// IN-ORDER -> fine-grained lgkmcnt(N), VGPR destinations, deep pipelining.
// EMPIRICAL VGPR LAW (R3/R6/R9/R10): this toolchain's arch-VGPR cap is
// 256/minWavesPerEU (NOT 512/minW): minW=8 -> 32, minW=4 -> 64. The LDS
// body needs ~100 VGPRs (weights moved from SGPR file to VGPR file), so
// minW MUST be 2 (cap 128). At minW=4 the body spilled acc+weights:
// WRITE 72.6 MB / FETCH 125 MB scratch signature, identical R9 vs R10.
__global__ __launch_bounds__(256, 2) void barrier_net(
    const float* __restrict__ x,
    const float* __restrict__ phi_w1, const float* __restrict__ phi_b1,
    const float* __restrict__ phi_w2, const float* __restrict__ phi_b2,
    const float* __restrict__ obs_w1, const float* __restrict__ obs_b1,
    const float* __restrict__ obs_w2, const float* __restrict__ obs_b2,
    const float* __restrict__ rho_w1, const float* __restrict__ rho_b1,
    const float* __restrict__ rho_w2, const float* __restrict__ rho_b2,
    const float* __restrict__ psi_w1, const float* __restrict__ psi_b1,
    const float* __restrict__ psi_w2, const float* __restrict__ psi_b2,
    float2* __restrict__ out)
{
    __shared__ float wlds[WTOT];

    // ---- cooperative weight staging: straight-line, SGPR pointers only ----
    {
        const int tx = threadIdx.x;
        wlds[PHI_W1 + tx] = phi_w1[tx];                      // 256
        wlds[PSI_W1 + tx] = psi_w1[tx];                      // 256
#pragma unroll
        for (int k = 0; k < 4; ++k) {                        // 1024 each
            wlds[PHI_W2 + 256 * k + tx] = phi_w2[256 * k + tx];
            wlds[OBS_W2 + 256 * k + tx] = obs_w2[256 * k + tx];
            wlds[RHO_W1 + 256 * k + tx] = rho_w1[256 * k + tx];
        }
        if (tx < 128) {
            wlds[OBS_W1 + tx] = obs_w1[tx];
            wlds[RHO_W2 + tx] = rho_w2[tx];
            wlds[PSI_W2 + tx] = psi_w2[tx];
        }
        if (tx < 64) {
            wlds[PHI_B1 + tx] = phi_b1[tx];
            wlds[OBS_B1 + tx] = obs_b1[tx];
            wlds[RHO_B1 + tx] = rho_b1[tx];
            wlds[PSI_B1 + tx] = psi_b1[tx];
        }
        if (tx < 16) {
            wlds[PHI_B2 + tx] = phi_b2[tx];
            wlds[OBS_B2 + tx] = obs_b2[tx];
        }
        if (tx < 2) {
            wlds[RHO_B2 + tx] = rho_b2[tx];
            wlds[PSI_B2 + tx] = psi_b2[tx];
        }
    }
    __syncthreads();

    const int tid = blockIdx.x * 256 + threadIdx.x;
    const int s = tid >> 1;
    const int t = tid & 1;
    if (s >= BATCH) return;
    const float* xr = x + (size_t)s * 85;

    auto L2 = [&](int i) -> v2 { return *(const v2*)(wlds + i); };

    // ---- per-lane slice: 8 neighbors, 4 observations ----
    float nb[8][4];
    const int nbase = 5 + 32 * t;
#pragma unroll
    for (int n = 0; n < 8; ++n)
#pragma unroll
        for (int k = 0; k < 4; ++k)
            nb[n][k] = xr[nbase + 4 * n + k];

    float ob[4][2];
    const int obase = 69 + 8 * t;
#pragma unroll
    for (int o = 0; o < 4; ++o) {
        ob[o][0] = xr[obase + 2 * o];
        ob[o][1] = xr[obase + 2 * o + 1];
    }

    const float g0 = xr[0], g1 = xr[1];

    // ---- barrier partial over my 8 neighbors ----
    float bar0 = 0.f, bar1 = 0.f;
#pragma unroll
    for (int n = 0; n < 8; ++n) {
        float p0 = -nb[n][0], p1 = -nb[n][1];
        float r  = __builtin_amdgcn_sqrtf(fmaf(p0, p0, p1 * p1));
        float sc = 0.01f * __builtin_amdgcn_rcpf(r - 0.2f);
        bar0 = fmaf(sc, p0, bar0);
        bar1 = fmaf(sc, p1, bar1);
    }

    // ---- acc partial (16 as 8 v2): each lane carries half the bias ----
    v2 acc[8];
#pragma unroll
    for (int p = 0; p < 8; ++p)
        acc[p] = fma2(splat(8.f), L2(PHI_B2 + 2 * p),
                 fma2(splat(4.f), L2(OBS_B2 + 2 * p), splat(0.f)));

    // ---- phi: chunks of 8 h ----
#pragma unroll 2
    for (int c = 0; c < 8; ++c) {
        const int hb = c * 8;
        v2 hsv[4] = {{0.f,0.f},{0.f,0.f},{0.f,0.f},{0.f,0.f}};
#pragma unroll
        for (int n = 0; n < 8; ++n) {
#pragma unroll
            for (int p = 0; p < 4; ++p) {
                v2 tv = fma2(splat(nb[n][0]), L2(PHI_W1 + hb + 2 * p),
                        fma2(splat(nb[n][1]), L2(PHI_W1 + 64 + hb + 2 * p),
                        fma2(splat(nb[n][2]), L2(PHI_W1 + 128 + hb + 2 * p),
                        fma2(splat(nb[n][3]), L2(PHI_W1 + 192 + hb + 2 * p),
                                              L2(PHI_B1 + hb + 2 * p)))));
                hsv[p] += relu2(tv);
            }
        }
#pragma unroll
        for (int p = 0; p < 4; ++p) {
            const int r0 = PHI_W2 + (hb + 2 * p) * 16;
            v2 hx = splat(hsv[p].x), hy = splat(hsv[p].y);
#pragma unroll
            for (int q = 0; q < 8; ++q)
                acc[q] = fma2(hy, L2(r0 + 16 + 2 * q),
                         fma2(hx, L2(r0 + 2 * q), acc[q]));
        }
    }

    // ---- obs: same chunking ----
#pragma unroll 2
    for (int c = 0; c < 8; ++c) {
        const int hb = c * 8;
        v2 hsv[4] = {{0.f,0.f},{0.f,0.f},{0.f,0.f},{0.f,0.f}};
#pragma unroll
        for (int o = 0; o < 4; ++o) {
#pragma unroll
            for (int p = 0; p < 4; ++p) {
                v2 tv = fma2(splat(ob[o][0]), L2(OBS_W1 + hb + 2 * p),
                        fma2(splat(ob[o][1]), L2(OBS_W1 + 64 + hb + 2 * p),
                                              L2(OBS_B1 + hb + 2 * p)));
                hsv[p] += relu2(tv);
            }
        }
#pragma unroll
        for (int p = 0; p < 4; ++p) {
            const int r0 = OBS_W2 + (hb + 2 * p) * 16;
            v2 hx = splat(hsv[p].x), hy = splat(hsv[p].y);
#pragma unroll
            for (int q = 0; q < 8; ++q)
                acc[q] = fma2(hy, L2(r0 + 16 + 2 * q),
                         fma2(hx, L2(r0 + 2 * q), acc[q]));
        }
    }

    // ---- pair-sum: acc + barrier ----
#pragma unroll
    for (int p = 0; p < 8; ++p) {
        acc[p].x += __shfl_xor(acc[p].x, 1);
        acc[p].y += __shfl_xor(acc[p].y, 1);
    }
    bar0 += __shfl_xor(bar0, 1);
    bar1 += __shfl_xor(bar1, 1);

    // ---- rho: 16 -> 64 -> 2, duplicated, chunked ----
    v2 rr = L2(RHO_B2);
#pragma unroll 2
    for (int c = 0; c < 8; ++c) {
        const int hb = c * 8;
        v2 tt[4];
#pragma unroll
        for (int p = 0; p < 4; ++p)
            tt[p] = L2(RHO_B1 + hb + 2 * p);
#pragma unroll
        for (int j = 0; j < 8; ++j) {
            v2 ax = splat(acc[j].x), ay = splat(acc[j].y);
            const int rj0 = RHO_W1 + (2 * j) * 64 + hb;
            const int rj1 = RHO_W1 + (2 * j + 1) * 64 + hb;
#pragma unroll
            for (int p = 0; p < 4; ++p)
                tt[p] = fma2(ay, L2(rj1 + 2 * p),
                        fma2(ax, L2(rj0 + 2 * p), tt[p]));
        }
#pragma unroll
        for (int p = 0; p < 4; ++p) {
            v2 u = relu2(tt[p]);
            rr = fma2(splat(u.x), L2(RHO_W2 + 2 * (hb + 2 * p)), rr);
            rr = fma2(splat(u.y), L2(RHO_W2 + 2 * (hb + 2 * p) + 2), rr);
        }
    }

    // ---- psi: [r0, r1, g0, g1] -> 64 -> 2, duplicated, chunked ----
    v2 ee = L2(PSI_B2);
#pragma unroll 2
    for (int c = 0; c < 8; ++c) {
        const int hb = c * 8;
#pragma unroll
        for (int p = 0; p < 4; ++p) {
            v2 tv = fma2(splat(rr.x), L2(PSI_W1 + hb + 2 * p),
                    fma2(splat(rr.y), L2(PSI_W1 + 64 + hb + 2 * p),
                    fma2(splat(g0),   L2(PSI_W1 + 128 + hb + 2 * p),
                    fma2(splat(g1),   L2(PSI_W1 + 192 + hb + 2 * p),
                                      L2(PSI_B1 + hb + 2 * p)))));
            v2 u = relu2(tv);
            ee = fma2(splat(u.x), L2(PSI_W2 + 2 * (hb + 2 * p)), ee);
            ee = fma2(splat(u.y), L2(PSI_W2 + 2 * (hb + 2 * p) + 2), ee);
        }
    }

    if (t == 0) {
        float a0 = tanhf(tanhf(ee.x) + bar0);
        float a1 = tanhf(tanhf(ee.y) + bar1);
        out[s] = make_float2(2.f * a0, 2.f * a1);
    }
}

extern "C" void kernel_launch(void* const* d_in, const int* in_sizes, int n_in,
                              void* d_out, int out_size, void* d_ws, size_t ws_size,
                              hipStream_t stream) {
    const int threads = BATCH * 2;
    dim3 grid((threads + 255) / 256), block(256);
    barrier_net<<<grid, block, 0, stream>>>(
        (const float*)d_in[0],
        (const float*)d_in[1],  (const float*)d_in[2],  (const float*)d_in[3],  (const float*)d_in[4],
        (const float*)d_in[5],  (const float*)d_in[6],  (const float*)d_in[7],  (const float*)d_in[8],
        (const float*)d_in[9],  (const float*)d_in[10], (const float*)d_in[11], (const float*)d_in[12],
        (const float*)d_in[13], (const float*)d_in[14], (const float*)d_in[15], (const float*)d_in[16],
        (float2*)d_out);
}

// Round 12
// 149.943 us; speedup vs baseline: 1.4177x; 1.0584x over previous
//
#include <hip/hip_runtime.h>

#define BATCH 100000

typedef float v2 __attribute__((ext_vector_type(2)));

__device__ __forceinline__ v2 fma2(v2 a, v2 b, v2 c) { return __builtin_elementwise_fma(a, b, c); }
__device__ __forceinline__ v2 relu2(v2 a) { v2 z = {0.f, 0.f}; return __builtin_elementwise_max(a, z); }
__device__ __forceinline__ v2 splat(float a) { v2 r = {a, a}; return r; }
__device__ __forceinline__ v2 ldv2(const float* p) { return *(const v2*)p; }

// 2 lanes per sample; lane t: phi neighbors [8t,8t+8), obs [4t,4t+4)
// (linearity: partial acc per lane, one shfl_xor to combine); rho/psi
// duplicated across the pair; weights via s_load (wave-uniform).
// R11 verdict: LDS-staged weights are WORSE (70 vs 54.5 us) - ~1060
// ds_read/wave x 12 waves/CU saturates the shared per-CU LDS pipe
// (~21 us of issue). s_load weight stream is the best of the tested
// broadcast paths.
// R12: block=64 (3125 one-wave blocks). R8's 782 four-wave blocks gave
// 3.05 blocks/CU -> 14 CUs run a 4th block while 242 idle (33% tail);
// measured time-avg occupancy 24% matches. One-wave blocks cut the
// remainder tail to ~1/12 and let the scheduler pack evenly.
// EMPIRICAL VGPR LAW (R3/R6/R9/R10/R11): arch-VGPR cap = 256/minWavesPerEU
// on this toolchain. minW=2 -> cap 128 >= natural ~64-84: no spill
// (tripwire: WRITE_SIZE must stay ~781 KB).
__global__ __launch_bounds__(64, 2) void barrier_net(
    const float* __restrict__ x,
    const float* __restrict__ phi_w1, const float* __restrict__ phi_b1,
    const float* __restrict__ phi_w2, const float* __restrict__ phi_b2,
    const float* __restrict__ obs_w1, const float* __restrict__ obs_b1,
    const float* __restrict__ obs_w2, const float* __restrict__ obs_b2,
    const float* __restrict__ rho_w1, const float* __restrict__ rho_b1,
    const float* __restrict__ rho_w2, const float* __restrict__ rho_b2,
    const float* __restrict__ psi_w1, const float* __restrict__ psi_b1,
    const float* __restrict__ psi_w2, const float* __restrict__ psi_b2,
    float2* __restrict__ out)
{
    const int tid = blockIdx.x * 64 + threadIdx.x;
    const int s = tid >> 1;
    const int t = tid & 1;
    if (s >= BATCH) return;
    const float* xr = x + (size_t)s * 85;

    // ---- per-lane slice: 8 neighbors, 4 observations ----
    float nb[8][4];
    const int nbase = 5 + 32 * t;
#pragma unroll
    for (int n = 0; n < 8; ++n)
#pragma unroll
        for (int k = 0; k < 4; ++k)
            nb[n][k] = xr[nbase + 4 * n + k];

    float ob[4][2];
    const int obase = 69 + 8 * t;
#pragma unroll
    for (int o = 0; o < 4; ++o) {
        ob[o][0] = xr[obase + 2 * o];
        ob[o][1] = xr[obase + 2 * o + 1];
    }

    const float g0 = xr[0], g1 = xr[1];

    // ---- barrier partial over my 8 neighbors ----
    float bar0 = 0.f, bar1 = 0.f;
#pragma unroll
    for (int n = 0; n < 8; ++n) {
        float p0 = -nb[n][0], p1 = -nb[n][1];
        float r  = __builtin_amdgcn_sqrtf(fmaf(p0, p0, p1 * p1));
        float sc = 0.01f * __builtin_amdgcn_rcpf(r - 0.2f);
        bar0 = fmaf(sc, p0, bar0);
        bar1 = fmaf(sc, p1, bar1);
    }

    // ---- acc partial (16 as 8 v2): each lane carries half the bias ----
    v2 acc[8];
#pragma unroll
    for (int p = 0; p < 8; ++p)
        acc[p] = fma2(splat(8.f), ldv2(phi_b2 + 2 * p),
                 fma2(splat(4.f), ldv2(obs_b2 + 2 * p), splat(0.f)));

    // ---- phi: chunks of 8 h; w1 row-segments + W2 rows all contiguous ----
#pragma unroll 2
    for (int c = 0; c < 8; ++c) {
        const int hb = c * 8;
        v2 hsv[4] = {{0.f,0.f},{0.f,0.f},{0.f,0.f},{0.f,0.f}};
#pragma unroll
        for (int n = 0; n < 8; ++n) {
#pragma unroll
            for (int p = 0; p < 4; ++p) {
                v2 tv = fma2(splat(nb[n][0]), ldv2(phi_w1 + hb + 2 * p),
                        fma2(splat(nb[n][1]), ldv2(phi_w1 + 64 + hb + 2 * p),
                        fma2(splat(nb[n][2]), ldv2(phi_w1 + 128 + hb + 2 * p),
                        fma2(splat(nb[n][3]), ldv2(phi_w1 + 192 + hb + 2 * p),
                                              ldv2(phi_b1 + hb + 2 * p)))));
                hsv[p] += relu2(tv);
            }
        }
#pragma unroll
        for (int p = 0; p < 4; ++p) {
            const float* r0 = phi_w2 + (size_t)(hb + 2 * p) * 16;
            v2 hx = splat(hsv[p].x), hy = splat(hsv[p].y);
#pragma unroll
            for (int q = 0; q < 8; ++q)
                acc[q] = fma2(hy, ldv2(r0 + 16 + 2 * q),
                         fma2(hx, ldv2(r0 + 2 * q), acc[q]));
        }
    }

    // ---- obs: same chunking ----
#pragma unroll 2
    for (int c = 0; c < 8; ++c) {
        const int hb = c * 8;
        v2 hsv[4] = {{0.f,0.f},{0.f,0.f},{0.f,0.f},{0.f,0.f}};
#pragma unroll
        for (int o = 0; o < 4; ++o) {
#pragma unroll
            for (int p = 0; p < 4; ++p) {
                v2 tv = fma2(splat(ob[o][0]), ldv2(obs_w1 + hb + 2 * p),
                        fma2(splat(ob[o][1]), ldv2(obs_w1 + 64 + hb + 2 * p),
                                              ldv2(obs_b1 + hb + 2 * p)));
                hsv[p] += relu2(tv);
            }
        }
#pragma unroll
        for (int p = 0; p < 4; ++p) {
            const float* r0 = obs_w2 + (size_t)(hb + 2 * p) * 16;
            v2 hx = splat(hsv[p].x), hy = splat(hsv[p].y);
#pragma unroll
            for (int q = 0; q < 8; ++q)
                acc[q] = fma2(hy, ldv2(r0 + 16 + 2 * q),
                         fma2(hx, ldv2(r0 + 2 * q), acc[q]));
        }
    }

    // ---- pair-sum: acc + barrier ----
#pragma unroll
    for (int p = 0; p < 8; ++p) {
        acc[p].x += __shfl_xor(acc[p].x, 1);
        acc[p].y += __shfl_xor(acc[p].y, 1);
    }
    bar0 += __shfl_xor(bar0, 1);
    bar1 += __shfl_xor(bar1, 1);

    // ---- rho: 16 -> 64 -> 2, duplicated, chunked (row-segment reads) ----
    v2 rr = ldv2(rho_b2);
#pragma unroll 2
    for (int c = 0; c < 8; ++c) {
        const int hb = c * 8;
        v2 tt[4];
#pragma unroll
        for (int p = 0; p < 4; ++p)
            tt[p] = ldv2(rho_b1 + hb + 2 * p);
#pragma unroll
        for (int j = 0; j < 8; ++j) {
            v2 ax = splat(acc[j].x), ay = splat(acc[j].y);
            const float* rj0 = rho_w1 + (size_t)(2 * j) * 64 + hb;
            const float* rj1 = rho_w1 + (size_t)(2 * j + 1) * 64 + hb;
#pragma unroll
            for (int p = 0; p < 4; ++p)
                tt[p] = fma2(ay, ldv2(rj1 + 2 * p),
                        fma2(ax, ldv2(rj0 + 2 * p), tt[p]));
        }
#pragma unroll
        for (int p = 0; p < 4; ++p) {
            v2 u = relu2(tt[p]);
            rr = fma2(splat(u.x), ldv2(rho_w2 + 2 * (hb + 2 * p)), rr);
            rr = fma2(splat(u.y), ldv2(rho_w2 + 2 * (hb + 2 * p) + 2), rr);
        }
    }

    // ---- psi: [r0, r1, g0, g1] -> 64 -> 2, duplicated, chunked ----
    v2 ee = ldv2(psi_b2);
#pragma unroll 2
    for (int c = 0; c < 8; ++c) {
        const int hb = c * 8;
#pragma unroll
        for (int p = 0; p < 4; ++p) {
            v2 tv = fma2(splat(rr.x), ldv2(psi_w1 + hb + 2 * p),
                    fma2(splat(rr.y), ldv2(psi_w1 + 64 + hb + 2 * p),
                    fma2(splat(g0),   ldv2(psi_w1 + 128 + hb + 2 * p),
                    fma2(splat(g1),   ldv2(psi_w1 + 192 + hb + 2 * p),
                                      ldv2(psi_b1 + hb + 2 * p)))));
            v2 u = relu2(tv);
            ee = fma2(splat(u.x), ldv2(psi_w2 + 2 * (hb + 2 * p)), ee);
            ee = fma2(splat(u.y), ldv2(psi_w2 + 2 * (hb + 2 * p) + 2), ee);
        }
    }

    if (t == 0) {
        float a0 = tanhf(tanhf(ee.x) + bar0);
        float a1 = tanhf(tanhf(ee.y) + bar1);
        out[s] = make_float2(2.f * a0, 2.f * a1);
    }
}

extern "C" void kernel_launch(void* const* d_in, const int* in_sizes, int n_in,
                              void* d_out, int out_size, void* d_ws, size_t ws_size,
                              hipStream_t stream) {
    const int threads = BATCH * 2;
    dim3 grid((threads + 63) / 64), block(64);
    barrier_net<<<grid, block, 0, stream>>>(
        (const float*)d_in[0],
        (const float*)d_in[1],  (const float*)d_in[2],  (const float*)d_in[3],  (const float*)d_in[4],
        (const float*)d_in[5],  (const float*)d_in[6],  (const float*)d_in[7],  (const float*)d_in[8],
        (const float*)d_in[9],  (const float*)d_in[10], (const float*)d_in[11], (const float*)d_in[12],
        (const float*)d_in[13], (const float*)d_in[14], (const float*)d_in[15], (const float*)d_in[16],
        (float2*)d_out);
}